// Round 12
// baseline (139.256 us; speedup 1.0000x reference)
//
#include <hip/hip_runtime.h>

// KPN fused, round 11 (resubmit after broker timeout): round-6 structure
// + 16B-slot involution swizzle on xcl (kills 4-way bank conflicts on both
// staging writes and B-frag reads) + s_setprio around the MFMA chains.

typedef __bf16 bf16x8 __attribute__((ext_vector_type(8)));
typedef float  f32x16 __attribute__((ext_vector_type(16)));
typedef unsigned int uint4v __attribute__((ext_vector_type(4)));

#define IMG   256
#define C_IN  16
#define LOG2E 1.4426950408889634f

#if __has_builtin(__builtin_amdgcn_exp2f)
#define EXP2(x) __builtin_amdgcn_exp2f(x)
#else
#define EXP2(x) __expf(0.69314718055994531f * (x))
#endif

#if __has_builtin(__builtin_amdgcn_rcpf)
#define RCP(x) __builtin_amdgcn_rcpf(x)
#else
#define RCP(x) (1.0f / (x))
#endif

__device__ __forceinline__ unsigned short f2bf(float f) {
  union { float f; unsigned int u; } v; v.f = f;
  unsigned int u = v.u;
  return (unsigned short)((u + 0x7FFFu + ((u >> 16) & 1u)) >> 16);  // RNE
}

__device__ __forceinline__ unsigned int cvt_pk_bf16(float lo, float hi) {
  unsigned int r;
  asm("v_cvt_pk_bf16_f32 %0, %1, %2" : "=v"(r) : "v"(lo), "v"(hi));
  return r;
}

// 16B-slot swizzle: involution, bijective within each 128B block.
// slot = 2*pixel + half; lanes reading stride-2 slots spread over all 8 bank groups.
__device__ __forceinline__ int swz16(int slot) {
  return (slot ^ ((slot >> 3) & 7)) << 4;
}

// ---------------- prepack ----------------
// apk[(c*9+pos)*64+lane] : bf16x8 A-frag, W[c*25+m, ci=8g+j, pos]*LOG2E (m=lane&31, pad rows 0)
// pb [(c*64+lane)]       : f32x16 bias frag, row=(r&3)+8(r>>2)+4g; pad rows -1e30
__global__ __launch_bounds__(256) void kpn_prepack(
    const float* __restrict__ cw, const float* __restrict__ cb,
    unsigned short* __restrict__ apk, float* __restrict__ pb)
{
  int t = blockIdx.x * 256 + threadIdx.x;
  if (t < 16 * 9 * 64) {                       // one thread per (c,pos,lane)
    int lane = t & 63, pc = t >> 6;
    int pos = pc % 9, c = pc / 9;
    int m = lane & 31, g = lane >> 5;
    unsigned short v8[8];
#pragma unroll
    for (int j = 0; j < 8; ++j) {
      int ci = 8 * g + j;
      float v = (m < 25) ? cw[((c * 25 + m) * 16 + ci) * 9 + pos] * LOG2E : 0.f;
      v8[j] = f2bf(v);
    }
    uint4v pk;
    pk[0] = (unsigned)v8[0] | ((unsigned)v8[1] << 16);
    pk[1] = (unsigned)v8[2] | ((unsigned)v8[3] << 16);
    pk[2] = (unsigned)v8[4] | ((unsigned)v8[5] << 16);
    pk[3] = (unsigned)v8[6] | ((unsigned)v8[7] << 16);
    *reinterpret_cast<uint4v*>(apk + t * 8) = pk;
  }
  int tb = t - 16 * 9 * 64;
  if (tb >= 0 && tb < 16 * 64) {               // one thread per (c,lane)
    int lane = tb & 63, c = tb >> 6, g = lane >> 5;
    f32x16 v;
#pragma unroll
    for (int r = 0; r < 16; ++r) {
      int row = (r & 3) + 8 * (r >> 2) + 4 * g;
      v[r] = (row < 25) ? cb[c * 25 + row] * LOG2E : -1e30f;
    }
    *reinterpret_cast<f32x16*>(pb + tb * 16) = v;
  }
}

// ---------------- main fused kernel ----------------
__global__ __launch_bounds__(256, 2) void kpn_main(
    const float* __restrict__ x,
    const unsigned short* __restrict__ apk,
    const float* __restrict__ pb,
    float* __restrict__ out)
{
  // B-frag tile: 16B slots, swizzled; slot = 2*pixel + half
  __shared__ char xclb[400 * 32];              // 12800 B
  // epilogue tile: channel-pair planar, u32 = (bf16 c_even | bf16 c_odd<<16), pitch 24
  __shared__ unsigned int ep[8 * 20 * 24];     // 15360 B

  const int tid  = threadIdx.x;
  const int w0   = blockIdx.x * 16;
  const int h0   = blockIdx.y * 16;
  const int nimg = blockIdx.z;

  // ---- staging: one thread per tile pixel, gather all 16 channels ----
  for (int p = tid; p < 400; p += 256) {
    int rr = p / 20, cc = p % 20;
    int gh = h0 + rr - 2, gw = w0 + cc - 2;
    float f[16];
    if (gh >= 0 && gh < IMG && gw >= 0 && gw < IMG) {
      const float* src = x + (size_t)nimg * C_IN * IMG * IMG + gh * IMG + gw;
#pragma unroll
      for (int ci = 0; ci < 16; ++ci) f[ci] = src[ci * IMG * IMG];
    } else {
#pragma unroll
      for (int ci = 0; ci < 16; ++ci) f[ci] = 0.f;
    }
    unsigned int u[8];
#pragma unroll
    for (int k = 0; k < 8; ++k) u[k] = cvt_pk_bf16(f[2 * k], f[2 * k + 1]);
    uint4v lo, hi;
    lo[0] = u[0]; lo[1] = u[1]; lo[2] = u[2]; lo[3] = u[3];
    hi[0] = u[4]; hi[1] = u[5]; hi[2] = u[6]; hi[3] = u[7];
    *reinterpret_cast<uint4v*>(xclb + swz16(2 * p))     = lo;   // half g=0
    *reinterpret_cast<uint4v*>(xclb + swz16(2 * p + 1)) = hi;   // half g=1
#pragma unroll
    for (int k = 0; k < 8; ++k) ep[k * 480 + rr * 24 + cc] = u[k];
  }
  __syncthreads();

  const int wave  = tid >> 6;
  const int lane  = tid & 63;
  const int g     = lane >> 5;
  const int n32   = lane & 31;
  const int px    = n32 & 15;
  const int py_in = n32 >> 4;

  // epilogue window u32-index offsets per D-reg (r = 0..12; invalid rows -> 0, killed by exp->0)
  int offs[13];
#pragma unroll
  for (int r = 0; r < 13; ++r) {
    int row = 4 * g + (r & 3) + 8 * (r >> 2);
    offs[r] = (row < 25) ? ((row / 5) * 24 + (row % 5)) : 0;
  }

  auto epi = [&](const f32x16& A0, const f32x16& A1, int c0, int py) {
    float s0 = 0.f, s1 = 0.f, ws0 = 0.f, ws1 = 0.f;
    const unsigned int* base = &ep[(c0 >> 1) * 480 + py * 24 + px];
#pragma unroll
    for (int r = 0; r < 13; ++r) {
      float e0 = EXP2(A0[r]);          // logits pre-scaled by log2e; pad rows -> exp2(-1e30)=0
      float e1 = EXP2(A1[r]);
      s0 += e0; s1 += e1;
      unsigned int u = base[offs[r]];
      union { unsigned int u; float f; } lo, hi;
      lo.u = u << 16; hi.u = u & 0xFFFF0000u;       // bf16 c0 (low), c0+1 (high)
      ws0 = fmaf(e0, lo.f, ws0);
      ws1 = fmaf(e1, hi.f, ws1);
    }
    s0 += __shfl_xor(s0, 32);  s1 += __shfl_xor(s1, 32);
    ws0 += __shfl_xor(ws0, 32); ws1 += __shfl_xor(ws1, 32);
    const int   ch  = c0 + g;
    const float val = (g == 0) ? (ws0 * RCP(s0)) : (ws1 * RCP(s1));
    out[(((size_t)nimg * C_IN + ch) * IMG + (h0 + py)) * IMG + (w0 + px)] = val;
  };

  const bf16x8* apv = reinterpret_cast<const bf16x8*>(apk);
  const f32x16* pbv = reinterpret_cast<const f32x16*>(pb);

  for (int pass = 0; pass < 2; ++pass) {
    const int c0 = wave * 4 + pass * 2;

    bf16x8 af0[9], af1[9];
#pragma unroll
    for (int pos = 0; pos < 9; ++pos) {
      af0[pos] = apv[(c0 * 9 + pos) * 64 + lane];
      af1[pos] = apv[((c0 + 1) * 9 + pos) * 64 + lane];
    }
    const f32x16 b0 = pbv[c0 * 64 + lane];
    const f32x16 b1 = pbv[(c0 + 1) * 64 + lane];

    for (int ntp = 0; ntp < 4; ++ntp) {
      const int pya = ntp * 4 + py_in;
      const int pyb = pya + 2;
      bf16x8 ba[9], bb[9];
#pragma unroll
      for (int kh = 0; kh < 3; ++kh)
#pragma unroll
        for (int kw = 0; kw < 3; ++kw) {
          int qa = (pya + 1 + kh) * 20 + (px + 1 + kw);
          int qb = (pyb + 1 + kh) * 20 + (px + 1 + kw);
          ba[kh * 3 + kw] = *reinterpret_cast<const bf16x8*>(xclb + swz16(2 * qa + g));
          bb[kh * 3 + kw] = *reinterpret_cast<const bf16x8*>(xclb + swz16(2 * qb + g));
        }
      __builtin_amdgcn_s_setprio(1);
      // bias rides in as C-operand of the first MFMA (no init movs, no epilogue adds)
      f32x16 Aa0 = __builtin_amdgcn_mfma_f32_32x32x16_bf16(af0[0], ba[0], b0, 0, 0, 0);
      f32x16 Aa1 = __builtin_amdgcn_mfma_f32_32x32x16_bf16(af1[0], ba[0], b1, 0, 0, 0);
      f32x16 Ab0 = __builtin_amdgcn_mfma_f32_32x32x16_bf16(af0[0], bb[0], b0, 0, 0, 0);
      f32x16 Ab1 = __builtin_amdgcn_mfma_f32_32x32x16_bf16(af1[0], bb[0], b1, 0, 0, 0);
#pragma unroll
      for (int pos = 1; pos < 9; ++pos) {
        Aa0 = __builtin_amdgcn_mfma_f32_32x32x16_bf16(af0[pos], ba[pos], Aa0, 0, 0, 0);
        Aa1 = __builtin_amdgcn_mfma_f32_32x32x16_bf16(af1[pos], ba[pos], Aa1, 0, 0, 0);
        Ab0 = __builtin_amdgcn_mfma_f32_32x32x16_bf16(af0[pos], bb[pos], Ab0, 0, 0, 0);
        Ab1 = __builtin_amdgcn_mfma_f32_32x32x16_bf16(af1[pos], bb[pos], Ab1, 0, 0, 0);
      }
      __builtin_amdgcn_s_setprio(0);
      epi(Aa0, Aa1, c0, pya);
      epi(Ab0, Ab1, c0, pyb);
    }
  }
}

extern "C" void kernel_launch(void* const* d_in, const int* in_sizes, int n_in,
                              void* d_out, int out_size, void* d_ws, size_t ws_size,
                              hipStream_t stream) {
  const float* x  = (const float*)d_in[0];
  const float* cw = (const float*)d_in[1];
  const float* cb = (const float*)d_in[2];
  float* out = (float*)d_out;

  unsigned short* apk = (unsigned short*)d_ws;                        // 147456 B
  float*          pb  = (float*)((char*)d_ws + 16 * 9 * 64 * 8 * 2);  //  65536 B

  kpn_prepack<<<40, 256, 0, stream>>>(cw, cb, apk, pb);

  dim3 grid(IMG / 16, IMG / 16, 4);   // 1024 blocks = 4/CU exactly
  kpn_main<<<grid, 256, 0, stream>>>(x, apk, pb, out);
}

// Round 14
// 117.907 us; speedup vs baseline: 1.1811x; 1.1811x over previous
//
#include <hip/hip_runtime.h>

// KPN fused, round 13 (resubmit after broker timeout): round-10 structure with
// xcl split into two g-planes (plane = 8 channels). Reads/writes become
// consecutive-16B-per-lane ds_b128 = canonical conflict-free pattern; addresses
// stay base + immediate offsets (no swizzle arithmetic -> no spill, unlike r12).

typedef __bf16 bf16x8 __attribute__((ext_vector_type(8)));
typedef float  f32x16 __attribute__((ext_vector_type(16)));
typedef unsigned int uint4v __attribute__((ext_vector_type(4)));

#define IMG   256
#define C_IN  16
#define LOG2E 1.4426950408889634f

#if __has_builtin(__builtin_amdgcn_exp2f)
#define EXP2(x) __builtin_amdgcn_exp2f(x)
#else
#define EXP2(x) __expf(0.69314718055994531f * (x))
#endif

#if __has_builtin(__builtin_amdgcn_rcpf)
#define RCP(x) __builtin_amdgcn_rcpf(x)
#else
#define RCP(x) (1.0f / (x))
#endif

__device__ __forceinline__ unsigned short f2bf(float f) {
  union { float f; unsigned int u; } v; v.f = f;
  unsigned int u = v.u;
  return (unsigned short)((u + 0x7FFFu + ((u >> 16) & 1u)) >> 16);  // RNE
}

__device__ __forceinline__ unsigned int cvt_pk_bf16(float lo, float hi) {
  unsigned int r;
  asm("v_cvt_pk_bf16_f32 %0, %1, %2" : "=v"(r) : "v"(lo), "v"(hi));
  return r;
}

// ---------------- prepack ----------------
// apk[(c*9+pos)*64+lane] : bf16x8 A-frag, W[c*25+m, ci=8g+j, pos]*LOG2E (m=lane&31, pad rows 0)
// pb [(c*64+lane)]       : f32x16 bias frag, row=(r&3)+8(r>>2)+4g; pad rows -1e30
__global__ __launch_bounds__(256) void kpn_prepack(
    const float* __restrict__ cw, const float* __restrict__ cb,
    unsigned short* __restrict__ apk, float* __restrict__ pb)
{
  int t = blockIdx.x * 256 + threadIdx.x;
  if (t < 16 * 9 * 64) {                       // one thread per (c,pos,lane)
    int lane = t & 63, pc = t >> 6;
    int pos = pc % 9, c = pc / 9;
    int m = lane & 31, g = lane >> 5;
    unsigned short v8[8];
#pragma unroll
    for (int j = 0; j < 8; ++j) {
      int ci = 8 * g + j;
      float v = (m < 25) ? cw[((c * 25 + m) * 16 + ci) * 9 + pos] * LOG2E : 0.f;
      v8[j] = f2bf(v);
    }
    uint4v pk;
    pk[0] = (unsigned)v8[0] | ((unsigned)v8[1] << 16);
    pk[1] = (unsigned)v8[2] | ((unsigned)v8[3] << 16);
    pk[2] = (unsigned)v8[4] | ((unsigned)v8[5] << 16);
    pk[3] = (unsigned)v8[6] | ((unsigned)v8[7] << 16);
    *reinterpret_cast<uint4v*>(apk + t * 8) = pk;
  }
  int tb = t - 16 * 9 * 64;
  if (tb >= 0 && tb < 16 * 64) {               // one thread per (c,lane)
    int lane = tb & 63, c = tb >> 6, g = lane >> 5;
    f32x16 v;
#pragma unroll
    for (int r = 0; r < 16; ++r) {
      int row = (r & 3) + 8 * (r >> 2) + 4 * g;
      v[r] = (row < 25) ? cb[c * 25 + row] * LOG2E : -1e30f;
    }
    *reinterpret_cast<f32x16*>(pb + tb * 16) = v;
  }
}

// ---------------- main fused kernel ----------------
__global__ __launch_bounds__(256, 2) void kpn_main(
    const float* __restrict__ x,
    const unsigned short* __restrict__ apk,
    const float* __restrict__ pb,
    float* __restrict__ out)
{
  // B-frag tile: two channel-half planes; plane g holds channels 8g..8g+7
  // (16 B per pixel). Consecutive lanes -> consecutive 16B slots: conflict-free.
  __shared__ char xg[2][400 * 16];             // 12800 B
  // epilogue tile: channel-pair planar, u32 = (bf16 c_even | bf16 c_odd<<16), pitch 24
  __shared__ unsigned int ep[8 * 20 * 24];     // 15360 B

  const int tid  = threadIdx.x;
  const int w0   = blockIdx.x * 16;
  const int h0   = blockIdx.y * 16;
  const int nimg = blockIdx.z;

  // ---- staging: one thread per tile pixel, gather all 16 channels ----
  for (int p = tid; p < 400; p += 256) {
    int rr = p / 20, cc = p % 20;
    int gh = h0 + rr - 2, gw = w0 + cc - 2;
    float f[16];
    if (gh >= 0 && gh < IMG && gw >= 0 && gw < IMG) {
      const float* src = x + (size_t)nimg * C_IN * IMG * IMG + gh * IMG + gw;
#pragma unroll
      for (int ci = 0; ci < 16; ++ci) f[ci] = src[ci * IMG * IMG];
    } else {
#pragma unroll
      for (int ci = 0; ci < 16; ++ci) f[ci] = 0.f;
    }
    unsigned int u[8];
#pragma unroll
    for (int k = 0; k < 8; ++k) u[k] = cvt_pk_bf16(f[2 * k], f[2 * k + 1]);
    uint4v lo, hi;
    lo[0] = u[0]; lo[1] = u[1]; lo[2] = u[2]; lo[3] = u[3];
    hi[0] = u[4]; hi[1] = u[5]; hi[2] = u[6]; hi[3] = u[7];
    *reinterpret_cast<uint4v*>(&xg[0][p * 16]) = lo;   // channels 0-7
    *reinterpret_cast<uint4v*>(&xg[1][p * 16]) = hi;   // channels 8-15
#pragma unroll
    for (int k = 0; k < 8; ++k) ep[k * 480 + rr * 24 + cc] = u[k];
  }
  __syncthreads();

  const int wave  = tid >> 6;
  const int lane  = tid & 63;
  const int g     = lane >> 5;
  const int n32   = lane & 31;
  const int px    = n32 & 15;
  const int py_in = n32 >> 4;

  // epilogue window u32-index offsets per D-reg (r = 0..12; invalid rows -> 0, killed by exp->0)
  int offs[13];
#pragma unroll
  for (int r = 0; r < 13; ++r) {
    int row = 4 * g + (r & 3) + 8 * (r >> 2);
    offs[r] = (row < 25) ? ((row / 5) * 24 + (row % 5)) : 0;
  }

  auto epi = [&](const f32x16& A0, const f32x16& A1, int c0, int py) {
    float s0 = 0.f, s1 = 0.f, ws0 = 0.f, ws1 = 0.f;
    const unsigned int* base = &ep[(c0 >> 1) * 480 + py * 24 + px];
#pragma unroll
    for (int r = 0; r < 13; ++r) {
      float e0 = EXP2(A0[r]);          // logits pre-scaled by log2e; pad rows -> exp2(-1e30)=0
      float e1 = EXP2(A1[r]);
      s0 += e0; s1 += e1;
      unsigned int u = base[offs[r]];
      union { unsigned int u; float f; } lo, hi;
      lo.u = u << 16; hi.u = u & 0xFFFF0000u;       // bf16 c0 (low), c0+1 (high)
      ws0 = fmaf(e0, lo.f, ws0);
      ws1 = fmaf(e1, hi.f, ws1);
    }
    s0 += __shfl_xor(s0, 32);  s1 += __shfl_xor(s1, 32);
    ws0 += __shfl_xor(ws0, 32); ws1 += __shfl_xor(ws1, 32);
    const int   ch  = c0 + g;
    const float val = (g == 0) ? (ws0 * RCP(s0)) : (ws1 * RCP(s1));
    out[(((size_t)nimg * C_IN + ch) * IMG + (h0 + py)) * IMG + (w0 + px)] = val;
  };

  const bf16x8* apv = reinterpret_cast<const bf16x8*>(apk);
  const f32x16* pbv = reinterpret_cast<const f32x16*>(pb);
  const char*   xgp = xg[g];           // this half-wave's channel plane

  for (int pass = 0; pass < 2; ++pass) {
    const int c0 = wave * 4 + pass * 2;

    bf16x8 af0[9], af1[9];
#pragma unroll
    for (int pos = 0; pos < 9; ++pos) {
      af0[pos] = apv[(c0 * 9 + pos) * 64 + lane];
      af1[pos] = apv[((c0 + 1) * 9 + pos) * 64 + lane];
    }
    const f32x16 b0 = pbv[c0 * 64 + lane];
    const f32x16 b1 = pbv[(c0 + 1) * 64 + lane];

    for (int ntp = 0; ntp < 4; ++ntp) {
      const int pya = ntp * 4 + py_in;
      const int pyb = pya + 2;
      // base pixel (pya+1, px+1); tap (kh,kw) adds compile-time (kh*20+kw)*16 bytes
      const char* pa = xgp + ((pya + 1) * 20 + (px + 1)) * 16;
      const char* pcb = xgp + ((pyb + 1) * 20 + (px + 1)) * 16;
      bf16x8 ba[9], bb[9];
#pragma unroll
      for (int kh = 0; kh < 3; ++kh)
#pragma unroll
        for (int kw = 0; kw < 3; ++kw) {
          ba[kh * 3 + kw] = *reinterpret_cast<const bf16x8*>(pa + (kh * 20 + kw) * 16);
          bb[kh * 3 + kw] = *reinterpret_cast<const bf16x8*>(pcb + (kh * 20 + kw) * 16);
        }
      // bias rides in as C-operand of the first MFMA (no init movs, no epilogue adds)
      f32x16 Aa0 = __builtin_amdgcn_mfma_f32_32x32x16_bf16(af0[0], ba[0], b0, 0, 0, 0);
      f32x16 Aa1 = __builtin_amdgcn_mfma_f32_32x32x16_bf16(af1[0], ba[0], b1, 0, 0, 0);
      f32x16 Ab0 = __builtin_amdgcn_mfma_f32_32x32x16_bf16(af0[0], bb[0], b0, 0, 0, 0);
      f32x16 Ab1 = __builtin_amdgcn_mfma_f32_32x32x16_bf16(af1[0], bb[0], b1, 0, 0, 0);
#pragma unroll
      for (int pos = 1; pos < 9; ++pos) {
        Aa0 = __builtin_amdgcn_mfma_f32_32x32x16_bf16(af0[pos], ba[pos], Aa0, 0, 0, 0);
        Aa1 = __builtin_amdgcn_mfma_f32_32x32x16_bf16(af1[pos], ba[pos], Aa1, 0, 0, 0);
        Ab0 = __builtin_amdgcn_mfma_f32_32x32x16_bf16(af0[pos], bb[pos], Ab0, 0, 0, 0);
        Ab1 = __builtin_amdgcn_mfma_f32_32x32x16_bf16(af1[pos], bb[pos], Ab1, 0, 0, 0);
      }
      epi(Aa0, Aa1, c0, pya);
      epi(Ab0, Ab1, c0, pyb);
    }
  }
}

extern "C" void kernel_launch(void* const* d_in, const int* in_sizes, int n_in,
                              void* d_out, int out_size, void* d_ws, size_t ws_size,
                              hipStream_t stream) {
  const float* x  = (const float*)d_in[0];
  const float* cw = (const float*)d_in[1];
  const float* cb = (const float*)d_in[2];
  float* out = (float*)d_out;

  unsigned short* apk = (unsigned short*)d_ws;                        // 147456 B
  float*          pb  = (float*)((char*)d_ws + 16 * 9 * 64 * 8 * 2);  //  65536 B

  kpn_prepack<<<40, 256, 0, stream>>>(cw, cb, apk, pb);

  dim3 grid(IMG / 16, IMG / 16, 4);   // 1024 blocks = 4/CU exactly
  kpn_main<<<grid, 256, 0, stream>>>(x, apk, pb, out);
}